// Round 2
// baseline (167.911 us; speedup 1.0000x reference)
//
#include <hip/hip_runtime.h>

// BlockConvolutionLean: out = blockwise-exclusive-cumsum(X @ W^T) + b_eff
// X: [65536, 256] fp32, W: [256, 256] fp32, bias: [8] fp32, out: [65536, 256] fp32
// Cumsum over groups of 8 consecutive rows; b_eff[i] = bias[i] + (i==0)*bias[0].
//
// R2 design: no LDS at all. W is pre-converted to bf16 in d_ws (128 KB,
// L2-resident); both A (fp32, packed in-flight) and B (bf16, direct 16B loads)
// fragments come straight from global in native MFMA layout. This lifts the
// LDS occupancy cap (R1: 64KB LDS -> 2 blocks/CU -> 2 waves/SIMD, latency-
// bound at 22% HBM) to 4 blocks/CU / 4 waves/SIMD, one exact tranche.

typedef short short8 __attribute__((ext_vector_type(8)));
typedef float floatx4 __attribute__((ext_vector_type(4)));
typedef unsigned short ushort4v __attribute__((ext_vector_type(4)));

__device__ __forceinline__ unsigned short f2bf(float f) {
    union { float f; unsigned int u; } v;
    v.f = f;
    unsigned int u = v.u + 0x7fffu + ((v.u >> 16) & 1u);  // RNE to bf16
    return (unsigned short)(u >> 16);
}

__device__ __forceinline__ short8 pack8(float4 f0, float4 f1) {
    short8 r;
    r[0] = (short)f2bf(f0.x); r[1] = (short)f2bf(f0.y);
    r[2] = (short)f2bf(f0.z); r[3] = (short)f2bf(f0.w);
    r[4] = (short)f2bf(f1.x); r[5] = (short)f2bf(f1.y);
    r[6] = (short)f2bf(f1.z); r[7] = (short)f2bf(f1.w);
    return r;
}

// ---- Kernel 1: W fp32 -> bf16 into workspace (256*256 elems) ----
__global__ __launch_bounds__(256) void wconv_kernel(
    const float* __restrict__ W, unsigned short* __restrict__ Wb)
{
    const int i = (blockIdx.x * 256 + threadIdx.x) * 4;
    float4 f = *(const float4*)(W + i);
    ushort4v v;
    v[0] = f2bf(f.x); v[1] = f2bf(f.y); v[2] = f2bf(f.z); v[3] = f2bf(f.w);
    *(ushort4v*)(Wb + i) = v;
}

// ---- Kernel 2: GEMM + blockwise exclusive cumsum epilogue ----
// WG = 256 threads = 4 waves, tile M=128 x N=128, wave tile 64x64.
__global__ __launch_bounds__(256, 4) void bcl_gemm_kernel(
    const float* __restrict__ X, const unsigned short* __restrict__ Wb,
    const float* __restrict__ bias, float* __restrict__ out)
{
    const int tid = threadIdx.x;
    const int bx  = blockIdx.x;
    const int mg  = bx >> 1;   // 0..511, M-group of 128 rows
    const int ng  = bx & 1;    // 0..1,  N-half of 128 cols

    const int lane = tid & 63;
    const int wave = tid >> 6;     // 0..3
    const int cl   = lane & 15;
    const int q    = lane >> 4;    // quad 0..3
    const int mw   = wave >> 1;    // 0..1
    const int nw   = wave & 1;     // 0..1

    floatx4 acc[4][4];
    #pragma unroll
    for (int mt = 0; mt < 4; ++mt)
        #pragma unroll
        for (int nt = 0; nt < 4; ++nt)
            acc[mt][nt] = (floatx4){0.f, 0.f, 0.f, 0.f};

    // A fragment: lane holds X[m = cl][k = q*8 + j], 8 consecutive fp32 (32B).
    const float* aBase = X + (size_t)(mg * 128 + mw * 64 + cl) * 256 + q * 8;
    // B fragment: lane holds W[n = cl][k = q*8 + j], 8 consecutive bf16 (16B).
    const unsigned short* bBase =
        Wb + (size_t)(ng * 128 + nw * 64 + cl) * 256 + q * 8;

    #pragma unroll
    for (int ks = 0; ks < 8; ++ks) {          // K = 256 = 8 x 32
        float4 af[4][2];
        short8 b[4];
        #pragma unroll
        for (int mt = 0; mt < 4; ++mt) {
            const float* p = aBase + mt * 16 * 256 + ks * 32;
            af[mt][0] = *(const float4*)p;
            af[mt][1] = *(const float4*)(p + 4);
        }
        #pragma unroll
        for (int nt = 0; nt < 4; ++nt)
            b[nt] = *(const short8*)(bBase + nt * 16 * 256 + ks * 32);
        short8 a[4];
        #pragma unroll
        for (int mt = 0; mt < 4; ++mt)
            a[mt] = pack8(af[mt][0], af[mt][1]);
        #pragma unroll
        for (int mt = 0; mt < 4; ++mt)
            #pragma unroll
            for (int nt = 0; nt < 4; ++nt)
                acc[mt][nt] = __builtin_amdgcn_mfma_f32_16x16x32_bf16(
                    a[mt], b[nt], acc[mt][nt], 0, 0, 0);
    }

    // ---- Epilogue: exclusive cumsum over 8-row blocks + bias, store ----
    // C/D layout: col = lane&15, row(in 16-tile) = q*4 + reg. Rows 0-7 live in
    // quads 0,1; rows 8-15 in quads 2,3. row%8 = (q&1)*4 + r.
    float be[4];
    {
        const int off = (q & 1) * 4;
        be[0] = bias[off + 0];
        be[1] = bias[off + 1];
        be[2] = bias[off + 2];
        be[3] = bias[off + 3];
        if (off == 0) be[0] += bias[0];   // b_eff[0] = 2*bias[0]
    }

    const int rowBase = mg * 128 + mw * 64 + q * 4;
    const int colBase = ng * 128 + nw * 64 + cl;
    #pragma unroll
    for (int mt = 0; mt < 4; ++mt) {
        #pragma unroll
        for (int nt = 0; nt < 4; ++nt) {
            floatx4 v = acc[mt][nt];
            float p1 = v[0];
            float p2 = p1 + v[1];
            float p3 = p2 + v[2];
            float tot = p3 + v[3];
            float below = __shfl_up(tot, 16);  // quad q-1's block total
            float p0 = 0.f;
            if (q & 1) { p0 = below; p1 += below; p2 += below; p3 += below; }
            float* o = out + (size_t)(rowBase + mt * 16) * 256 + colBase + nt * 16;
            o[0]   = p0 + be[0];
            o[256] = p1 + be[1];
            o[512] = p2 + be[2];
            o[768] = p3 + be[3];
        }
    }
}

extern "C" void kernel_launch(void* const* d_in, const int* in_sizes, int n_in,
                              void* d_out, int out_size, void* d_ws, size_t ws_size,
                              hipStream_t stream)
{
    const float* X = (const float*)d_in[0];  // seq_vector [8*8192, 256]
    const float* W = (const float*)d_in[1];  // [256, 256]
    const float* B = (const float*)d_in[2];  // [8]
    float* out = (float*)d_out;              // [8*8192, 256]
    unsigned short* Wb = (unsigned short*)d_ws;  // 256*256 bf16 = 128 KB

    wconv_kernel<<<dim3(64), dim3(256), 0, stream>>>(W, Wb);
    bcl_gemm_kernel<<<dim3(1024), dim3(256), 0, stream>>>(X, Wb, B, out);
}

// Round 3
// 144.142 us; speedup vs baseline: 1.1649x; 1.1649x over previous
//
#include <hip/hip_runtime.h>

// BlockConvolutionLean: out = blockwise-exclusive-cumsum(X @ W^T) + b_eff
// X: [65536, 256] fp32, W: [256, 256] fp32, bias: [8] fp32, out: [65536, 256] fp32
//
// R3 theory: R1/R2 both hit a ~2 TB/s HBM wall (invariant under 2x occupancy):
// every HBM access was 16-64B granules at 1 KB row stride (MFMA fragment
// scatter). R3 makes ALL HBM traffic contiguous full-line streams:
//   - A staged via async global_load_lds (full 128B lines, sequential rows),
//     triple-buffered K=32 chunks, ZERO barriers (wave-private 32-row slabs).
//   - Source-gather XOR swizzle so the forced LDS landing layout gives
//     conflict-free ds_read_b128 fragment reads.
//   - Stores transposed through wave-private LDS -> contiguous 512B/row
//     dwordx4 streams (fixes R2's 37% write inflation).
//   - B (bf16 W in d_ws) direct from global, L2-resident.

typedef short short8 __attribute__((ext_vector_type(8)));
typedef float floatx4 __attribute__((ext_vector_type(4)));
typedef unsigned short ushort4v __attribute__((ext_vector_type(4)));

typedef const __attribute__((address_space(1))) unsigned int* gas_u32p;
typedef __attribute__((address_space(3))) unsigned int* las_u32p;

// s_waitcnt with only vmcnt constrained (gfx9 encoding: vm[3:0]|[15:14],
// exp[6:4]=7, lgkm[11:8]=15)
#define WAIT_VMCNT(n) __builtin_amdgcn_s_waitcnt(0x0F70 | ((n) & 0xF) | ((((n) >> 4) & 0x3) << 14))

__device__ __forceinline__ void gl2lds16(const float* g, float* l) {
    __builtin_amdgcn_global_load_lds((gas_u32p)(const void*)g, (las_u32p)(void*)l, 16, 0, 0);
}

__device__ __forceinline__ unsigned short f2bf(float f) {
    union { float f; unsigned int u; } v;
    v.f = f;
    unsigned int u = v.u + 0x7fffu + ((v.u >> 16) & 1u);  // RNE to bf16
    return (unsigned short)(u >> 16);
}

__device__ __forceinline__ short8 pack8(float4 f0, float4 f1) {
    short8 r;
    r[0] = (short)f2bf(f0.x); r[1] = (short)f2bf(f0.y);
    r[2] = (short)f2bf(f0.z); r[3] = (short)f2bf(f0.w);
    r[4] = (short)f2bf(f1.x); r[5] = (short)f2bf(f1.y);
    r[6] = (short)f2bf(f1.z); r[7] = (short)f2bf(f1.w);
    return r;
}

// ---- Kernel 1: W fp32 -> bf16 into workspace ----
__global__ __launch_bounds__(256) void wconv_kernel(
    const float* __restrict__ W, unsigned short* __restrict__ Wb)
{
    const int i = (blockIdx.x * 256 + threadIdx.x) * 4;
    float4 f = *(const float4*)(W + i);
    ushort4v v;
    v[0] = f2bf(f.x); v[1] = f2bf(f.y); v[2] = f2bf(f.z); v[3] = f2bf(f.w);
    *(ushort4v*)(Wb + i) = v;
}

// ---- Kernel 2: GEMM + blockwise exclusive cumsum epilogue ----
// Block: 256 thr = 4 waves. Block tile M=128 x N=128; wave = 32-row strip
// (rows mg*128 + w*32, all 128 cols). acc: 2 mt x 8 nt x f32x4 = 64 AGPR.
__global__ __launch_bounds__(256) void bcl_gemm_kernel(
    const float* __restrict__ X, const unsigned short* __restrict__ Wb,
    const float* __restrict__ bias, float* __restrict__ out)
{
    __shared__ float buf[3][128 * 32];   // 3 x 16 KB chunk buffers [128 rows][32 K]

    const int tid  = threadIdx.x;
    const int lane = tid & 63;
    const int w    = tid >> 6;          // wave 0..3
    const int bx   = blockIdx.x;
    const int mg   = bx >> 1;           // 0..511
    const int ng   = bx & 1;            // N-half

    const int cl = lane & 15;
    const int q  = lane >> 4;

    // Staging geometry: per round j, wave covers 8 rows x 128B (full lines).
    // lane i -> row i>>3, 16B segment (i&7)^(i>>3)  [source-gather swizzle:
    // physical LDS slot p of row r holds logical slot p ^ (r&7)].
    const int srow = lane >> 3;
    const int sseg = (lane & 7) ^ srow;
    const float* gsrc0 = X + (size_t)(mg * 128 + w * 32 + srow) * 256 + sseg * 4;

    // chunk c staged into buf[c%3]; rounds j=0..3 cover rows w*32+j*8..+8
#define STAGE(c, b)                                                            \
    do {                                                                       \
        const float* _g = gsrc0 + (c) * 32;                                    \
        _Pragma("unroll")                                                      \
        for (int _j = 0; _j < 4; ++_j)                                         \
            gl2lds16(_g + _j * 8 * 256, &buf[b][(w * 32 + _j * 8) * 32]);      \
    } while (0)

    // B fragment: lane holds Wb[n = nt*16+cl][k = c*32 + q*8 ..+8] (16B load)
    const unsigned short* bBase = Wb + (size_t)(ng * 128 + cl) * 256 + q * 8;

    floatx4 acc[2][8];
    #pragma unroll
    for (int mt = 0; mt < 2; ++mt)
        #pragma unroll
        for (int nt = 0; nt < 8; ++nt)
            acc[mt][nt] = (floatx4){0.f, 0.f, 0.f, 0.f};

    STAGE(0, 0);
    STAGE(1, 1);

    #pragma unroll
    for (int c = 0; c < 8; ++c) {       // K = 256 = 8 chunks of 32
        // stage(c) is 2 chunk-times old; allow stage(c+1)'s 4 loads in flight
        WAIT_VMCNT(4);
        __builtin_amdgcn_sched_barrier(0);

        short8 Bf[8];
        #pragma unroll
        for (int nt = 0; nt < 8; ++nt)
            Bf[nt] = *(const short8*)(bBase + nt * 16 * 256 + c * 32);

        // A fragment from LDS: row mt*16+cl of slab, logical slots q*2, q*2+1
        float4 af[2][2];
        #pragma unroll
        for (int mt = 0; mt < 2; ++mt)
            #pragma unroll
            for (int h = 0; h < 2; ++h)
                af[mt][h] = *(const float4*)
                    &buf[c % 3][(w * 32 + mt * 16 + cl) * 32 +
                                ((((q << 1) | h) ^ (cl & 7)) << 2)];

        if (c + 2 < 8) STAGE(c + 2, (c + 2) % 3);  // buffer (c+2)%3 != c%3

        short8 a[2];
        a[0] = pack8(af[0][0], af[0][1]);
        a[1] = pack8(af[1][0], af[1][1]);

        #pragma unroll
        for (int mt = 0; mt < 2; ++mt)
            #pragma unroll
            for (int nt = 0; nt < 8; ++nt)
                acc[mt][nt] = __builtin_amdgcn_mfma_f32_16x16x32_bf16(
                    a[mt], Bf[nt], acc[mt][nt], 0, 0, 0);
    }

    // ---- Epilogue: cumsum + bias, transpose via wave-private LDS, stream out
    // C/D layout: col = cl, tile-row = q*4 + reg; row%8 = (q&1)*4 + reg.
    float be[4];
    {
        const int off = (q & 1) * 4;
        be[0] = bias[off + 0];
        be[1] = bias[off + 1];
        be[2] = bias[off + 2];
        be[3] = bias[off + 3];
        if (off == 0) be[0] += bias[0];   // b_eff[0] = 2*bias[0]
    }

    float* epi = &buf[0][w * 32 * 32];   // wave-private 4 KB (8 rows x 128 f32)

    #pragma unroll
    for (int p = 0; p < 4; ++p) {        // 8-row group p: mt = p>>1, half = p&1
        const int mt = p >> 1;
        const bool act = ((q >> 1) == (p & 1));
        #pragma unroll
        for (int nt = 0; nt < 8; ++nt) {
            floatx4 v = acc[mt][nt];
            float p1 = v[0];
            float p2 = p1 + v[1];
            float p3 = p2 + v[2];
            float tot = p3 + v[3];
            float below = __shfl_up(tot, 16);   // previous quad's block total
            float p0 = 0.f;
            if (q & 1) { p0 = below; p1 += below; p2 += below; p3 += below; }
            if (act) {
                float* dst = epi + (q & 1) * 4 * 128 + nt * 16 + cl;
                dst[0]   = p0 + be[0];
                dst[128] = p1 + be[1];
                dst[256] = p2 + be[2];
                dst[384] = p3 + be[3];
            }
        }
        // read back rows, store contiguous 512B per out row (dwordx4 stream)
        #pragma unroll
        for (int k = 0; k < 4; ++k) {
            const int r   = k * 2 + (lane >> 5);   // 0..7
            const int c32 = lane & 31;
            floatx4 vv = *(const floatx4*)&epi[r * 128 + c32 * 4];
            const size_t grow = (size_t)(mg * 128 + w * 32 + p * 8 + r);
            *(floatx4*)&out[grow * 256 + ng * 128 + c32 * 4] = vv;
        }
    }
#undef STAGE
}

extern "C" void kernel_launch(void* const* d_in, const int* in_sizes, int n_in,
                              void* d_out, int out_size, void* d_ws, size_t ws_size,
                              hipStream_t stream)
{
    const float* X = (const float*)d_in[0];  // seq_vector [8*8192, 256]
    const float* W = (const float*)d_in[1];  // [256, 256]
    const float* B = (const float*)d_in[2];  // [8]
    float* out = (float*)d_out;              // [8*8192, 256]
    unsigned short* Wb = (unsigned short*)d_ws;  // 256*256 bf16 = 128 KB

    wconv_kernel<<<dim3(64), dim3(256), 0, stream>>>(W, Wb);
    bcl_gemm_kernel<<<dim3(1024), dim3(256), 0, stream>>>(X, Wb, B, out);
}